// Round 2
// baseline (5986.979 us; speedup 1.0000x reference)
//
#include <hip/hip_runtime.h>

#define T_ 256
#define B_ 128
#define I_ 1024
#define H_ 1024
#define G_ 4096   // 4*H
#define BH (B_*H_)   // 131072
#define TB (T_*B_)   // 32768

typedef float f32x4 __attribute__((ext_vector_type(4)));
typedef short bf16x8 __attribute__((ext_vector_type(8)));

__device__ inline unsigned short f2bf(float f) {
    union { float f; unsigned int u; } v; v.f = f;
    unsigned int u = v.u;
    unsigned int r = (u + 0x7fffu + ((u >> 16) & 1u)) >> 16;
    return (unsigned short)r;
}
__device__ inline float bf2f(unsigned short s) {
    union { unsigned int u; float f; } v; v.u = ((unsigned int)s) << 16;
    return v.f;
}
__device__ inline float sigmoidf_(float x) { return 1.0f / (1.0f + __expf(-x)); }
__device__ inline float tanhf_(float x) {
    x = fminf(15.0f, fmaxf(-15.0f, x));
    float e = __expf(2.0f * x);
    return (e - 1.0f) / (e + 1.0f);
}

// ---------------- convert fp32 -> bf16 (vectorized) ----------------
__global__ void cvt_kernel(const float* __restrict__ src, unsigned short* __restrict__ dst, int n) {
    int i = (blockIdx.x * blockDim.x + threadIdx.x) * 4;
    int stride = gridDim.x * blockDim.x * 4;
    for (; i < n; i += stride) {
        float4 v = *reinterpret_cast<const float4*>(src + i);
        ushort4 o;
        o.x = f2bf(v.x); o.y = f2bf(v.y); o.z = f2bf(v.z); o.w = f2bf(v.w);
        *reinterpret_cast<ushort4*>(dst + i) = o;
    }
}

__global__ void bias_kernel(const float* __restrict__ a, const float* __restrict__ b, float* __restrict__ out) {
    int i = blockIdx.x * blockDim.x + threadIdx.x;
    if (i < G_) out[i] = a[i] + b[i];
}

// ---------------- pre-GEMM: gates_x = x @ Wih^T + bias  (bf16 out) ----------------
__global__ __launch_bounds__(256) void pregemm(
    const unsigned short* __restrict__ xb,   // [32768][1024] bf16
    const unsigned short* __restrict__ wih,  // [4096][1024] bf16
    const float* __restrict__ bias,          // [4096]
    unsigned short* __restrict__ gx)         // [32768][4096] bf16
{
    int wgid = (blockIdx.x & 7) * 1024 + (blockIdx.x >> 3);
    int mg = wgid & 255;
    int ng = wgid >> 8;
    int m0 = mg * 128, n0 = ng * 128;
    int tid = threadIdx.x;
    int w = tid >> 6, l = tid & 63;
    int qm = (w >> 1) * 64, qn = (w & 1) * 64;
    int lr = l & 15, lk = (l >> 4) * 8, lq = l >> 4;

    const unsigned short* ap = xb  + (size_t)(m0 + qm + lr) * I_ + lk;
    const unsigned short* bp = wih + (size_t)(n0 + qn + lr) * I_ + lk;

    f32x4 acc[4][4] = {};
    #pragma unroll 4
    for (int kk = 0; kk < 32; ++kk) {
        bf16x8 a[4], b[4];
        #pragma unroll
        for (int mt = 0; mt < 4; ++mt)
            a[mt] = *reinterpret_cast<const bf16x8*>(ap + (size_t)mt * 16 * I_ + kk * 32);
        #pragma unroll
        for (int nt = 0; nt < 4; ++nt)
            b[nt] = *reinterpret_cast<const bf16x8*>(bp + (size_t)nt * 16 * I_ + kk * 32);
        #pragma unroll
        for (int mt = 0; mt < 4; ++mt)
            #pragma unroll
            for (int nt = 0; nt < 4; ++nt)
                acc[mt][nt] = __builtin_amdgcn_mfma_f32_16x16x32_bf16(a[mt], b[nt], acc[mt][nt], 0, 0, 0);
    }
    #pragma unroll
    for (int mt = 0; mt < 4; ++mt) {
        #pragma unroll
        for (int nt = 0; nt < 4; ++nt) {
            #pragma unroll
            for (int r = 0; r < 4; ++r) {
                int m = m0 + qm + mt * 16 + lq * 4 + r;
                int n = n0 + qn + nt * 16 + lr;
                gx[(size_t)m * G_ + n] = f2bf(acc[mt][nt][r] + bias[n]);
            }
        }
    }
}

// ---------------- hierarchical grid barrier ----------------
// bar layout (unsigned words): 16 leaves at stride 32 (128B apart),
// mid at [512], gen at [544]. All monotonic; zeroed per call.
__device__ __forceinline__ void grid_barrier(unsigned* bar, int step, int bid) {
    __syncthreads();
    if (threadIdx.x == 0) {
        __threadfence();  // release: h writes -> visible device-wide
        unsigned target = (unsigned)(step * 16 + 15);
        unsigned old = atomicAdd(bar + (bid & 15) * 32, 1u);
        if (old == target) {
            unsigned mold = atomicAdd(bar + 512, 1u);
            if (mold == target) {
                __hip_atomic_store(bar + 544, (unsigned)(step + 1),
                                   __ATOMIC_RELEASE, __HIP_MEMORY_SCOPE_AGENT);
            }
        }
        while (__hip_atomic_load(bar + 544, __ATOMIC_RELAXED, __HIP_MEMORY_SCOPE_AGENT)
               < (unsigned)(step + 1)) {
            __builtin_amdgcn_s_sleep(2);
        }
        __threadfence();  // acquire: invalidate stale h lines
    }
    __syncthreads();
}

// ---------------- persistent recurrent kernel: all 256 steps ----------------
// 256 blocks x 512 threads. Block owns 32 batch rows x 16 h-cols.
// Wave w: gate g=w&3, K-half kh=w>>2; 2 M-tiles (chains of 16 MFMA).
// c lives in a register (1 element/thread); h double-buffered in global bf16.
__global__ __launch_bounds__(512) void lstm_recur(
    const unsigned short* __restrict__ whh,   // [4096][1024] bf16
    const unsigned short* __restrict__ gx,    // [32768][4096] bf16
    const float* __restrict__ c0,             // [128][1024]
    unsigned short* __restrict__ hbuf,        // [2][128][1024] bf16 (buf 0 = h0)
    float* __restrict__ ys,                   // [256][128][1024]
    float* __restrict__ hT, float* __restrict__ cT,
    unsigned* __restrict__ bar)
{
    __shared__ float lds_g[2][4][32][16];   // [khalf][gate][row][col]
    const int bid = blockIdx.x;
    const int mg = bid >> 6, ng = bid & 63;
    const int m0 = mg * 32, n0 = ng * 16;
    const int tid = threadIdx.x;
    const int w = tid >> 6, l = tid & 63;
    const int g = w & 3, kh = w >> 2;
    const int lr = l & 15, lk8 = (l >> 4) * 8, lq = l >> 4;

    // elementwise identity: 512 threads -> 32x16 tile
    const int erow = tid >> 4, ecol = tid & 15;
    const size_t eoff = (size_t)(m0 + erow) * H_ + n0 + ecol;
    float c = c0[eoff];
    const unsigned short* gxp = gx + (size_t)(m0 + erow) * G_ + n0 + ecol;

    // B-fragment pointer: Whh rows for gate g, this block's 16 h-cols, K-half kh
    const unsigned short* bp = whh + (size_t)(g * 1024 + n0 + lr) * H_ + kh * 512 + lk8;

    // prefetch gx for t=0
    unsigned short gx0 = gxp[0], gx1 = gxp[1024], gx2 = gxp[2048], gx3 = gxp[3072];

    for (int t = 0; t < T_; ++t) {
        const unsigned short* hp = hbuf + (size_t)(t & 1) * BH
                                 + (size_t)(m0 + lr) * H_ + kh * 512 + lk8;
        f32x4 acc0 = {}, acc1 = {};
        #pragma unroll
        for (int kk = 0; kk < 16; ++kk) {
            bf16x8 bb = *reinterpret_cast<const bf16x8*>(bp + kk * 32);
            bf16x8 a0 = *reinterpret_cast<const bf16x8*>(hp + kk * 32);
            bf16x8 a1 = *reinterpret_cast<const bf16x8*>(hp + (size_t)16 * H_ + kk * 32);
            acc0 = __builtin_amdgcn_mfma_f32_16x16x32_bf16(a0, bb, acc0, 0, 0, 0);
            acc1 = __builtin_amdgcn_mfma_f32_16x16x32_bf16(a1, bb, acc1, 0, 0, 0);
        }
        #pragma unroll
        for (int r = 0; r < 4; ++r) {
            lds_g[kh][g][lq * 4 + r][lr]      = acc0[r];
            lds_g[kh][g][16 + lq * 4 + r][lr] = acc1[r];
        }
        __syncthreads();

        float gi = lds_g[0][0][erow][ecol] + lds_g[1][0][erow][ecol] + bf2f(gx0);
        float gf = lds_g[0][1][erow][ecol] + lds_g[1][1][erow][ecol] + bf2f(gx1);
        float gg = lds_g[0][2][erow][ecol] + lds_g[1][2][erow][ecol] + bf2f(gx2);
        float go = lds_g[0][3][erow][ecol] + lds_g[1][3][erow][ecol] + bf2f(gx3);
        float iv = sigmoidf_(gi);
        float fv = sigmoidf_(gf);
        float gv = tanhf_(gg);
        float ov = sigmoidf_(go);
        c = fv * c + iv * gv;
        float hn = ov * tanhf_(c);

        ys[(size_t)t * BH + eoff] = hn;
        hbuf[(size_t)((t + 1) & 1) * BH + eoff] = f2bf(hn);
        if (t == T_ - 1) { hT[eoff] = hn; cT[eoff] = c; }

        // prefetch next step's gx (in flight across the barrier)
        if (t + 1 < T_) {
            const unsigned short* p = gxp + (size_t)(t + 1) * B_ * G_;
            gx0 = p[0]; gx1 = p[1024]; gx2 = p[2048]; gx3 = p[3072];
        }

        grid_barrier(bar, t, bid);
    }
}

extern "C" void kernel_launch(void* const* d_in, const int* in_sizes, int n_in,
                              void* d_out, int out_size, void* d_ws, size_t ws_size,
                              hipStream_t stream)
{
    const float* x   = (const float*)d_in[0];
    const float* h0  = (const float*)d_in[1];
    const float* c0  = (const float*)d_in[2];
    const float* Wih = (const float*)d_in[3];
    const float* Whh = (const float*)d_in[4];
    const float* bih = (const float*)d_in[5];
    const float* bhh = (const float*)d_in[6];

    // workspace layout (bytes)
    char* ws = (char*)d_ws;
    unsigned short* gx   = (unsigned short*)(ws);                 // 256 MB
    unsigned short* xb   = (unsigned short*)(ws + 268435456);     //  64 MB
    unsigned short* wihb = (unsigned short*)(ws + 335544320);     //   8 MB
    unsigned short* whhb = (unsigned short*)(ws + 343932928);     //   8 MB
    unsigned short* hbuf = (unsigned short*)(ws + 352321536);     // 512 KB: h dbuf bf16
    float*          bias = (float*)(ws + 352845824);              //  16 KB
    unsigned*       bar  = (unsigned*)(ws + 352862208);           //   4 KB barrier

    float* out = (float*)d_out;
    float* ys = out;                           // [256][128][1024]
    float* hT = out + (size_t)TB * H_;         // [128][1024]
    float* cT = hT + BH;                       // [128][1024]

    hipMemsetAsync(bar, 0, 4096, stream);
    cvt_kernel<<<2048, 256, 0, stream>>>(x,   xb,   TB * I_);
    cvt_kernel<<<512,  256, 0, stream>>>(Wih, wihb, G_ * I_);
    cvt_kernel<<<512,  256, 0, stream>>>(Whh, whhb, G_ * H_);
    cvt_kernel<<<128,  256, 0, stream>>>(h0,  hbuf, BH);   // hbuf[0] = h0
    bias_kernel<<<16, 256, 0, stream>>>(bih, bhh, bias);

    pregemm<<<8192, 256, 0, stream>>>(xb, wihb, bias, gx);

    lstm_recur<<<256, 512, 0, stream>>>(whhb, gx, c0, hbuf, ys, hT, cT, bar);
}

// Round 4
// 5295.832 us; speedup vs baseline: 1.1305x; 1.1305x over previous
//
#include <hip/hip_runtime.h>

#define T_ 256
#define B_ 128
#define I_ 1024
#define H_ 1024
#define G_ 4096   // 4*H
#define BH (B_*H_)   // 131072
#define TB (T_*B_)   // 32768

typedef float f32x4 __attribute__((ext_vector_type(4)));
typedef short bf16x8 __attribute__((ext_vector_type(8)));

__device__ inline unsigned short f2bf(float f) {
    union { float f; unsigned int u; } v; v.f = f;
    unsigned int u = v.u;
    unsigned int r = (u + 0x7fffu + ((u >> 16) & 1u)) >> 16;
    return (unsigned short)r;
}
__device__ inline float bf2f(unsigned short s) {
    union { unsigned int u; float f; } v; v.u = ((unsigned int)s) << 16;
    return v.f;
}
__device__ inline float sigmoidf_(float x) { return 1.0f / (1.0f + __expf(-x)); }
__device__ inline float tanhf_(float x) {
    x = fminf(15.0f, fmaxf(-15.0f, x));
    float e = __expf(2.0f * x);
    return (e - 1.0f) / (e + 1.0f);
}

// ---------------- convert fp32 -> bf16 (vectorized) ----------------
__global__ void cvt_kernel(const float* __restrict__ src, unsigned short* __restrict__ dst, int n) {
    int i = (blockIdx.x * blockDim.x + threadIdx.x) * 4;
    int stride = gridDim.x * blockDim.x * 4;
    for (; i < n; i += stride) {
        float4 v = *reinterpret_cast<const float4*>(src + i);
        ushort4 o;
        o.x = f2bf(v.x); o.y = f2bf(v.y); o.z = f2bf(v.z); o.w = f2bf(v.w);
        *reinterpret_cast<ushort4*>(dst + i) = o;
    }
}

__global__ void bias_kernel(const float* __restrict__ a, const float* __restrict__ b, float* __restrict__ out) {
    int i = blockIdx.x * blockDim.x + threadIdx.x;
    if (i < G_) out[i] = a[i] + b[i];
}

// ---------------- pre-GEMM: gates_x = x @ Wih^T + bias  (bf16 out) ----------------
__global__ __launch_bounds__(256) void pregemm(
    const unsigned short* __restrict__ xb,   // [32768][1024] bf16
    const unsigned short* __restrict__ wih,  // [4096][1024] bf16
    const float* __restrict__ bias,          // [4096]
    unsigned short* __restrict__ gx)         // [32768][4096] bf16
{
    int wgid = (blockIdx.x & 7) * 1024 + (blockIdx.x >> 3);
    int mg = wgid & 255;
    int ng = wgid >> 8;
    int m0 = mg * 128, n0 = ng * 128;
    int tid = threadIdx.x;
    int w = tid >> 6, l = tid & 63;
    int qm = (w >> 1) * 64, qn = (w & 1) * 64;
    int lr = l & 15, lk = (l >> 4) * 8, lq = l >> 4;

    const unsigned short* ap = xb  + (size_t)(m0 + qm + lr) * I_ + lk;
    const unsigned short* bp = wih + (size_t)(n0 + qn + lr) * I_ + lk;

    f32x4 acc[4][4] = {};
    #pragma unroll 4
    for (int kk = 0; kk < 32; ++kk) {
        bf16x8 a[4], b[4];
        #pragma unroll
        for (int mt = 0; mt < 4; ++mt)
            a[mt] = *reinterpret_cast<const bf16x8*>(ap + (size_t)mt * 16 * I_ + kk * 32);
        #pragma unroll
        for (int nt = 0; nt < 4; ++nt)
            b[nt] = *reinterpret_cast<const bf16x8*>(bp + (size_t)nt * 16 * I_ + kk * 32);
        #pragma unroll
        for (int mt = 0; mt < 4; ++mt)
            #pragma unroll
            for (int nt = 0; nt < 4; ++nt)
                acc[mt][nt] = __builtin_amdgcn_mfma_f32_16x16x32_bf16(a[mt], b[nt], acc[mt][nt], 0, 0, 0);
    }
    #pragma unroll
    for (int mt = 0; mt < 4; ++mt) {
        #pragma unroll
        for (int nt = 0; nt < 4; ++nt) {
            #pragma unroll
            for (int r = 0; r < 4; ++r) {
                int m = m0 + qm + mt * 16 + lq * 4 + r;
                int n = n0 + qn + nt * 16 + lr;
                gx[(size_t)m * G_ + n] = f2bf(acc[mt][nt][r] + bias[n]);
            }
        }
    }
}

// ---------------- fence-free grid barrier (agent-scope atomics only) ----------------
__device__ __forceinline__ void grid_barrier(unsigned* bar, int step, int bid) {
    __syncthreads();   // drains vmcnt: all sc1 h-stores are at the coherence point
    if (threadIdx.x == 0) {
        unsigned target = (unsigned)(step * 16 + 15);
        unsigned old = __hip_atomic_fetch_add(bar + (bid & 15) * 32, 1u,
                                              __ATOMIC_RELAXED, __HIP_MEMORY_SCOPE_AGENT);
        if (old == target) {
            unsigned mold = __hip_atomic_fetch_add(bar + 512, 1u,
                                                   __ATOMIC_RELAXED, __HIP_MEMORY_SCOPE_AGENT);
            if (mold == target) {
                __hip_atomic_store(bar + 544, (unsigned)(step + 1),
                                   __ATOMIC_RELAXED, __HIP_MEMORY_SCOPE_AGENT);
            }
        }
        while (__hip_atomic_load(bar + 544, __ATOMIC_RELAXED, __HIP_MEMORY_SCOPE_AGENT)
               < (unsigned)(step + 1)) {
            __builtin_amdgcn_s_sleep(1);
        }
    }
    __syncthreads();
}

// ---------------- persistent recurrent kernel: all 256 steps ----------------
// 256 blocks x 512 threads. Block owns 32 batch rows x 16 h-cols (x 4 gates).
// Whh slice in LDS for all steps, k-major layout [ck 0..127][row 0..63][8 bf16]
// -> linear addressing (no swizzle), conflict-free ds_read_b128.
// Wave w: m-half mh=w>>2, gate g=w&3; K=1024 chain, 4 interleaved accumulators.
// c in a register; h exchanged via agent-scope (L3-coherent) loads/stores, no fences.
__global__ __launch_bounds__(512) void lstm_recur(
    const unsigned short* __restrict__ whh,   // [4096][1024] bf16
    const unsigned short* __restrict__ gx,    // [32768][4096] bf16
    const float* __restrict__ c0,             // [128][1024]
    unsigned short* __restrict__ hbuf,        // [2][128][1024] bf16 (buf 0 = h0)
    float* __restrict__ ys,                   // [256][128][1024]
    float* __restrict__ hT, float* __restrict__ cT,
    unsigned* __restrict__ bar)
{
    __shared__ unsigned short whh_lds[8192 * 8];   // 128 KB: [ck][row][8]
    __shared__ float lds_g[4][32][17];             // ~8.7 KB, padded

    const int bid = blockIdx.x;
    const int mg = bid >> 6, ng = bid & 63;   // 4 m-groups x 64 col-groups
    const int m0 = mg * 32, n0 = ng * 16;
    const int tid = threadIdx.x;
    const int w = tid >> 6, l = tid & 63;
    const int mh = w >> 2, g = w & 3;
    const int lr = l & 15, lkidx = l >> 4, lk8 = (l >> 4) * 8;

    // ---- stage Whh slice into LDS once ----
    // dest chunk# = ck*64 + row ; row = g*16 + c (c = col within block's 16 cols)
    for (int it = 0; it < 16; ++it) {
        int idx = it * 512 + tid;          // 0..8191 chunks of 16B
        int row = idx >> 7;                // 0..63
        int ck  = idx & 127;               // k-octet within the row
        int gg = row >> 4, cc = row & 15;
        bf16x8 v = *reinterpret_cast<const bf16x8*>(
            whh + (size_t)(gg * 1024 + n0 + cc) * H_ + ck * 8);
        *reinterpret_cast<bf16x8*>(whh_lds + ((size_t)ck * 64 + row) * 8) = v;
    }
    __syncthreads();

    // B-fragment LDS base: row = g*16 + lr, k-octet = lkidx (+ 4 per kk step)
    const unsigned short* bbase = whh_lds + ((size_t)lkidx * 64 + g * 16 + lr) * 8;

    // elementwise identity: 512 threads -> 32x16 tile
    const int erow = tid >> 4, ecol = tid & 15;
    const size_t eoff = (size_t)(m0 + erow) * H_ + n0 + ecol;
    float c = c0[eoff];
    const unsigned short* gxp = gx + (size_t)(m0 + erow) * G_ + n0 + ecol;

    // prefetch gx for t=0
    unsigned short gx0 = gxp[0], gx1 = gxp[1024], gx2 = gxp[2048], gx3 = gxp[3072];

    for (int t = 0; t < T_; ++t) {
        // ---- gate GEMM: A = h rows (agent-scope 8B loads), B = Whh from LDS ----
        unsigned long long* hp = (unsigned long long*)(
            hbuf + (size_t)(t & 1) * BH + (size_t)(m0 + mh * 16 + lr) * H_ + lk8);
        f32x4 acc[4] = {};
        #pragma unroll
        for (int kk = 0; kk < 32; ++kk) {
            union { unsigned long long q[2]; bf16x8 v; } ua;
            ua.q[0] = __hip_atomic_load(hp + kk * 8,     __ATOMIC_RELAXED, __HIP_MEMORY_SCOPE_AGENT);
            ua.q[1] = __hip_atomic_load(hp + kk * 8 + 1, __ATOMIC_RELAXED, __HIP_MEMORY_SCOPE_AGENT);
            bf16x8 bb = *reinterpret_cast<const bf16x8*>(bbase + kk * 2048);  // +4096 B
            acc[kk & 3] = __builtin_amdgcn_mfma_f32_16x16x32_bf16(ua.v, bb, acc[kk & 3], 0, 0, 0);
        }
        #pragma unroll
        for (int r = 0; r < 4; ++r)
            lds_g[g][mh * 16 + lkidx * 4 + r][lr] = (acc[0][r] + acc[1][r]) + (acc[2][r] + acc[3][r]);
        __syncthreads();

        // ---- fused elementwise ----
        float gi = lds_g[0][erow][ecol] + bf2f(gx0);
        float gf = lds_g[1][erow][ecol] + bf2f(gx1);
        float gg = lds_g[2][erow][ecol] + bf2f(gx2);
        float go = lds_g[3][erow][ecol] + bf2f(gx3);
        float iv = sigmoidf_(gi);
        float fv = sigmoidf_(gf);
        float gv = tanhf_(gg);
        float ov = sigmoidf_(go);
        c = fv * c + iv * gv;
        float hn = ov * tanhf_(c);

        ys[(size_t)t * BH + eoff] = hn;

        // h store: pair lanes -> one 4B agent-scope store (L3-coherent)
        unsigned short* hbn = hbuf + (size_t)((t + 1) & 1) * BH;
        float hn_o = __shfl_xor(hn, 1);
        if ((tid & 1) == 0) {
            unsigned u = (unsigned)f2bf(hn) | (((unsigned)f2bf(hn_o)) << 16);
            __hip_atomic_store((unsigned*)(hbn + eoff), u,
                               __ATOMIC_RELAXED, __HIP_MEMORY_SCOPE_AGENT);
        }
        if (t == T_ - 1) { hT[eoff] = hn; cT[eoff] = c; }

        // prefetch next step's gx, then barrier
        if (t + 1 < T_) {
            const unsigned short* p = gxp + (size_t)(t + 1) * B_ * G_;
            gx0 = p[0]; gx1 = p[1024]; gx2 = p[2048]; gx3 = p[3072];
            grid_barrier(bar, t, bid);
        }
    }
}

extern "C" void kernel_launch(void* const* d_in, const int* in_sizes, int n_in,
                              void* d_out, int out_size, void* d_ws, size_t ws_size,
                              hipStream_t stream)
{
    const float* x   = (const float*)d_in[0];
    const float* h0  = (const float*)d_in[1];
    const float* c0  = (const float*)d_in[2];
    const float* Wih = (const float*)d_in[3];
    const float* Whh = (const float*)d_in[4];
    const float* bih = (const float*)d_in[5];
    const float* bhh = (const float*)d_in[6];

    // workspace layout (bytes)
    char* ws = (char*)d_ws;
    unsigned short* gx   = (unsigned short*)(ws);                 // 256 MB
    unsigned short* xb   = (unsigned short*)(ws + 268435456);     //  64 MB
    unsigned short* wihb = (unsigned short*)(ws + 335544320);     //   8 MB
    unsigned short* whhb = (unsigned short*)(ws + 343932928);     //   8 MB
    unsigned short* hbuf = (unsigned short*)(ws + 352321536);     // 512 KB: h dbuf bf16
    float*          bias = (float*)(ws + 352845824);              //  16 KB
    unsigned*       bar  = (unsigned*)(ws + 352862208);           //   4 KB barrier

    float* out = (float*)d_out;
    float* ys = out;                           // [256][128][1024]
    float* hT = out + (size_t)TB * H_;         // [128][1024]
    float* cT = hT + BH;                       // [128][1024]

    hipMemsetAsync(bar, 0, 4096, stream);
    cvt_kernel<<<2048, 256, 0, stream>>>(x,   xb,   TB * I_);
    cvt_kernel<<<512,  256, 0, stream>>>(Wih, wihb, G_ * I_);
    cvt_kernel<<<512,  256, 0, stream>>>(Whh, whhb, G_ * H_);
    cvt_kernel<<<128,  256, 0, stream>>>(h0,  hbuf, BH);   // hbuf[0] = h0
    bias_kernel<<<16, 256, 0, stream>>>(bih, bhh, bias);

    pregemm<<<8192, 256, 0, stream>>>(xb, wihb, bias, gx);

    lstm_recur<<<256, 512, 0, stream>>>(whhb, gx, c0, hbuf, ys, hT, cT, bar);
}

// Round 5
// 5160.501 us; speedup vs baseline: 1.1602x; 1.0262x over previous
//
#include <hip/hip_runtime.h>

#define T_ 256
#define B_ 128
#define I_ 1024
#define H_ 1024
#define G_ 4096   // 4*H
#define BH (B_*H_)   // 131072
#define TB (T_*B_)   // 32768

typedef float f32x4 __attribute__((ext_vector_type(4)));
typedef short bf16x8 __attribute__((ext_vector_type(8)));

__device__ inline unsigned short f2bf(float f) {
    union { float f; unsigned int u; } v; v.f = f;
    unsigned int u = v.u;
    unsigned int r = (u + 0x7fffu + ((u >> 16) & 1u)) >> 16;
    return (unsigned short)r;
}
__device__ inline float bf2f(unsigned short s) {
    union { unsigned int u; float f; } v; v.u = ((unsigned int)s) << 16;
    return v.f;
}
__device__ inline float sigmoidf_(float x) { return 1.0f / (1.0f + __expf(-x)); }
__device__ inline float tanhf_(float x) {
    x = fminf(15.0f, fmaxf(-15.0f, x));
    float e = __expf(2.0f * x);
    return (e - 1.0f) / (e + 1.0f);
}

// ---------------- convert fp32 -> bf16 (vectorized) ----------------
__global__ void cvt_kernel(const float* __restrict__ src, unsigned short* __restrict__ dst, int n) {
    int i = (blockIdx.x * blockDim.x + threadIdx.x) * 4;
    int stride = gridDim.x * blockDim.x * 4;
    for (; i < n; i += stride) {
        float4 v = *reinterpret_cast<const float4*>(src + i);
        ushort4 o;
        o.x = f2bf(v.x); o.y = f2bf(v.y); o.z = f2bf(v.z); o.w = f2bf(v.w);
        *reinterpret_cast<ushort4*>(dst + i) = o;
    }
}

__global__ void bias_kernel(const float* __restrict__ a, const float* __restrict__ b, float* __restrict__ out) {
    int i = blockIdx.x * blockDim.x + threadIdx.x;
    if (i < G_) out[i] = a[i] + b[i];
}

// ---------------- pre-GEMM: gates_x = x @ Wih^T + bias  (bf16 out) ----------------
__global__ __launch_bounds__(256) void pregemm(
    const unsigned short* __restrict__ xb,   // [32768][1024] bf16
    const unsigned short* __restrict__ wih,  // [4096][1024] bf16
    const float* __restrict__ bias,          // [4096]
    unsigned short* __restrict__ gx)         // [32768][4096] bf16
{
    int wgid = (blockIdx.x & 7) * 1024 + (blockIdx.x >> 3);
    int mg = wgid & 255;
    int ng = wgid >> 8;
    int m0 = mg * 128, n0 = ng * 128;
    int tid = threadIdx.x;
    int w = tid >> 6, l = tid & 63;
    int qm = (w >> 1) * 64, qn = (w & 1) * 64;
    int lr = l & 15, lk = (l >> 4) * 8, lq = l >> 4;

    const unsigned short* ap = xb  + (size_t)(m0 + qm + lr) * I_ + lk;
    const unsigned short* bp = wih + (size_t)(n0 + qn + lr) * I_ + lk;

    f32x4 acc[4][4] = {};
    #pragma unroll 4
    for (int kk = 0; kk < 32; ++kk) {
        bf16x8 a[4], b[4];
        #pragma unroll
        for (int mt = 0; mt < 4; ++mt)
            a[mt] = *reinterpret_cast<const bf16x8*>(ap + (size_t)mt * 16 * I_ + kk * 32);
        #pragma unroll
        for (int nt = 0; nt < 4; ++nt)
            b[nt] = *reinterpret_cast<const bf16x8*>(bp + (size_t)nt * 16 * I_ + kk * 32);
        #pragma unroll
        for (int mt = 0; mt < 4; ++mt)
            #pragma unroll
            for (int nt = 0; nt < 4; ++nt)
                acc[mt][nt] = __builtin_amdgcn_mfma_f32_16x16x32_bf16(a[mt], b[nt], acc[mt][nt], 0, 0, 0);
    }
    #pragma unroll
    for (int mt = 0; mt < 4; ++mt) {
        #pragma unroll
        for (int nt = 0; nt < 4; ++nt) {
            #pragma unroll
            for (int r = 0; r < 4; ++r) {
                int m = m0 + qm + mt * 16 + lq * 4 + r;
                int n = n0 + qn + nt * 16 + lr;
                gx[(size_t)m * G_ + n] = f2bf(acc[mt][nt][r] + bias[n]);
            }
        }
    }
}

// ---------------- per-group barrier: 64 blocks, 8 leaves x 8 ----------------
// gbar: this group's 2KB region (512 words). Leaves at word leaf*32 (leaf<8),
// mid at word 256, generation at word 288. Monotonic counters, zeroed per call.
__device__ __forceinline__ void group_barrier(unsigned* gbar, int step, int ing) {
    __syncthreads();   // drains vmcnt: all sc1 h-stores at coherence point
    if (threadIdx.x == 0) {
        unsigned target = (unsigned)(step * 8 + 7);
        unsigned old = __hip_atomic_fetch_add(gbar + (ing & 7) * 32, 1u,
                                              __ATOMIC_RELAXED, __HIP_MEMORY_SCOPE_AGENT);
        if (old == target) {
            unsigned mold = __hip_atomic_fetch_add(gbar + 256, 1u,
                                                   __ATOMIC_RELAXED, __HIP_MEMORY_SCOPE_AGENT);
            if (mold == target) {
                __hip_atomic_store(gbar + 288, (unsigned)(step + 1),
                                   __ATOMIC_RELAXED, __HIP_MEMORY_SCOPE_AGENT);
            }
        }
        while (__hip_atomic_load(gbar + 288, __ATOMIC_RELAXED, __HIP_MEMORY_SCOPE_AGENT)
               < (unsigned)(step + 1)) {
            __builtin_amdgcn_s_sleep(1);
        }
    }
    __syncthreads();
}

// ---------------- persistent recurrent kernel: all 256 steps ----------------
// 256 blocks x 512 threads; block (mg,ng) owns 32 batch rows x 16 h-cols x 4 gates.
// bid -> (mg = (bid&7)>>1, ng = (bid>>3)*2 + (bid&1)): each mg-group of 64 blocks
// sits on 2 XCDs and exchanges h ONLY within itself -> independent group barriers.
// Whh slice in LDS (k-major [ck][row][8], linear, conflict-free).
// Waves = (mh, kq): disjoint k-quarter h loads (batched atomics, all in flight),
// partials for all 4 gates reduced via ds_add_f32 into lds_g.
__global__ __launch_bounds__(512) void lstm_recur(
    const unsigned short* __restrict__ whh,   // [4096][1024] bf16
    const unsigned short* __restrict__ gx,    // [32768][4096] bf16
    const float* __restrict__ c0,             // [128][1024]
    unsigned short* __restrict__ hbuf,        // [2][128][1024] bf16 (buf 0 = h0)
    float* __restrict__ ys,                   // [256][128][1024]
    float* __restrict__ hT, float* __restrict__ cT,
    unsigned* __restrict__ bar)
{
    __shared__ unsigned short whh_lds[8192 * 8];   // 128 KB: [ck][row][8]
    __shared__ float lds_g[4][32][16];             // 8 KB gate accumulators

    const int bid = blockIdx.x;
    const int mg  = (bid & 7) >> 1;               // group / m-tile, pinned to XCD pair
    const int ing = (bid >> 3) * 2 + (bid & 1);   // in-group index = ng, 0..63
    const int m0 = mg * 32, n0 = ing * 16;
    unsigned* gbar = bar + mg * 512;

    const int tid = threadIdx.x;
    const int w = tid >> 6, l = tid & 63;
    const int mh = w >> 2, kq = w & 3;            // wave roles: m-half, k-quarter
    const int lr = l & 15, lkidx = l >> 4;

    // ---- stage Whh slice into LDS once: chunk# = ck*64 + row, row = g*16 + c ----
    for (int it = 0; it < 16; ++it) {
        int idx = it * 512 + tid;          // 0..8191 chunks of 16B
        int row = idx >> 7;                // 0..63
        int ck  = idx & 127;               // k-octet
        int gg = row >> 4, cc = row & 15;
        bf16x8 v = *reinterpret_cast<const bf16x8*>(
            whh + (size_t)(gg * 1024 + n0 + cc) * H_ + ck * 8);
        *reinterpret_cast<bf16x8*>(whh_lds + ((size_t)ck * 64 + row) * 8) = v;
    }
    __syncthreads();

    // B-frag base: ck = kq*32 + kk*4 + lkidx, row = g*16 + lr
    // addr(shorts) = base + kk*2048 + g*128
    const unsigned short* bwave = whh_lds + (((size_t)(kq * 32 + lkidx)) * 64 + lr) * 8;

    // elementwise identity: 512 threads -> 32x16 tile
    const int erow = tid >> 4, ecol = tid & 15;
    const size_t eoff = (size_t)(m0 + erow) * H_ + n0 + ecol;
    float c = c0[eoff];
    const unsigned short* gxp = gx + (size_t)(m0 + erow) * G_ + n0 + ecol;

    // A-row base offset (element units, without buffer select)
    const size_t hrow = (size_t)(m0 + mh * 16 + lr) * H_ + kq * 256;

    // prefetch gx for t=0
    unsigned short gx0 = gxp[0], gx1 = gxp[1024], gx2 = gxp[2048], gx3 = gxp[3072];

    for (int t = 0; t < T_; ++t) {
        // ---- batched h loads: 16 agent-scope 8B loads, all in flight ----
        const unsigned long long* hp64 = (const unsigned long long*)(
            hbuf + (size_t)(t & 1) * BH + hrow) + lkidx * 2;
        unsigned long long hq[16];
        #pragma unroll
        for (int kk = 0; kk < 8; ++kk) {
            hq[2*kk]   = __hip_atomic_load(hp64 + kk * 8,     __ATOMIC_RELAXED, __HIP_MEMORY_SCOPE_AGENT);
            hq[2*kk+1] = __hip_atomic_load(hp64 + kk * 8 + 1, __ATOMIC_RELAXED, __HIP_MEMORY_SCOPE_AGENT);
        }

        // zero gate accumulators while loads fly (2048 floats / 512 threads)
        {
            float* lg = (float*)lds_g;
            lg[tid] = 0.f; lg[tid + 512] = 0.f; lg[tid + 1024] = 0.f; lg[tid + 1536] = 0.f;
        }

        // ---- MFMA: partials for all 4 gates over this wave's k-quarter ----
        f32x4 acc[4] = {};
        #pragma unroll
        for (int kk = 0; kk < 8; ++kk) {
            union { unsigned long long q[2]; bf16x8 v; } ua;
            ua.q[0] = hq[2*kk]; ua.q[1] = hq[2*kk+1];
            #pragma unroll
            for (int g = 0; g < 4; ++g) {
                bf16x8 bbv = *reinterpret_cast<const bf16x8*>(bwave + kk * 2048 + g * 128);
                acc[g] = __builtin_amdgcn_mfma_f32_16x16x32_bf16(ua.v, bbv, acc[g], 0, 0, 0);
            }
        }
        __syncthreads();   // zeros complete before any ds_add

        #pragma unroll
        for (int g = 0; g < 4; ++g)
            #pragma unroll
            for (int r = 0; r < 4; ++r)
                atomicAdd(&lds_g[g][mh * 16 + lkidx * 4 + r][lr], acc[g][r]);
        __syncthreads();   // sums complete

        // ---- fused elementwise ----
        float gi = lds_g[0][erow][ecol] + bf2f(gx0);
        float gf = lds_g[1][erow][ecol] + bf2f(gx1);
        float gg = lds_g[2][erow][ecol] + bf2f(gx2);
        float go = lds_g[3][erow][ecol] + bf2f(gx3);
        float iv = sigmoidf_(gi);
        float fv = sigmoidf_(gf);
        float gv = tanhf_(gg);
        float ov = sigmoidf_(go);
        c = fv * c + iv * gv;
        float hn = ov * tanhf_(c);

        ys[(size_t)t * BH + eoff] = hn;

        // h store: pair lanes -> one 4B agent-scope store (L3-coherent)
        unsigned short* hbn = hbuf + (size_t)((t + 1) & 1) * BH;
        float hn_o = __shfl_xor(hn, 1);
        if ((tid & 1) == 0) {
            unsigned u = (unsigned)f2bf(hn) | (((unsigned)f2bf(hn_o)) << 16);
            __hip_atomic_store((unsigned*)(hbn + eoff), u,
                               __ATOMIC_RELAXED, __HIP_MEMORY_SCOPE_AGENT);
        }
        if (t == T_ - 1) { hT[eoff] = hn; cT[eoff] = c; }

        // prefetch next step's gx, then group barrier
        if (t + 1 < T_) {
            const unsigned short* p = gxp + (size_t)(t + 1) * B_ * G_;
            gx0 = p[0]; gx1 = p[1024]; gx2 = p[2048]; gx3 = p[3072];
            group_barrier(gbar, t, ing);
        }
    }
}

extern "C" void kernel_launch(void* const* d_in, const int* in_sizes, int n_in,
                              void* d_out, int out_size, void* d_ws, size_t ws_size,
                              hipStream_t stream)
{
    const float* x   = (const float*)d_in[0];
    const float* h0  = (const float*)d_in[1];
    const float* c0  = (const float*)d_in[2];
    const float* Wih = (const float*)d_in[3];
    const float* Whh = (const float*)d_in[4];
    const float* bih = (const float*)d_in[5];
    const float* bhh = (const float*)d_in[6];

    // workspace layout (bytes)
    char* ws = (char*)d_ws;
    unsigned short* gx   = (unsigned short*)(ws);                 // 256 MB
    unsigned short* xb   = (unsigned short*)(ws + 268435456);     //  64 MB
    unsigned short* wihb = (unsigned short*)(ws + 335544320);     //   8 MB
    unsigned short* whhb = (unsigned short*)(ws + 343932928);     //   8 MB
    unsigned short* hbuf = (unsigned short*)(ws + 352321536);     // 512 KB: h dbuf bf16
    float*          bias = (float*)(ws + 352845824);              //  16 KB
    unsigned*       bar  = (unsigned*)(ws + 352862208);           //   8 KB barrier (4 groups x 2KB)

    float* out = (float*)d_out;
    float* ys = out;                           // [256][128][1024]
    float* hT = out + (size_t)TB * H_;         // [128][1024]
    float* cT = hT + BH;                       // [128][1024]

    hipMemsetAsync(bar, 0, 8192, stream);
    cvt_kernel<<<2048, 256, 0, stream>>>(x,   xb,   TB * I_);
    cvt_kernel<<<512,  256, 0, stream>>>(Wih, wihb, G_ * I_);
    cvt_kernel<<<512,  256, 0, stream>>>(Whh, whhb, G_ * H_);
    cvt_kernel<<<128,  256, 0, stream>>>(h0,  hbuf, BH);   // hbuf[0] = h0
    bias_kernel<<<16, 256, 0, stream>>>(bih, bhh, bias);

    pregemm<<<8192, 256, 0, stream>>>(xb, wihb, bias, gx);

    lstm_recur<<<256, 512, 0, stream>>>(whhb, gx, c0, hbuf, ys, hT, cT, bar);
}